// Round 8
// baseline (3670.345 us; speedup 1.0000x reference)
//
#include <hip/hip_runtime.h>
#include <hip/hip_bf16.h>

#define T_STEPS 512
#define BATCH   256
#define HID     100
#define GATES   400   // 4*H
#define BT      (BATCH * T_STEPS)

__device__ __forceinline__ float sigm_f(float x) {
    return 1.f / (1.f + __expf(-x));
}

__device__ __forceinline__ float tanh_f(float x) {
    float ax = fabsf(x);
    float t  = __expf(-2.f * ax);
    float r  = (1.f - t) / (1.f + t);
    return copysignf(r, x);
}

// ---------------------------------------------------------------------------
// xg GEMM v4: BM=128, BN=128, BK=20, 8x8 microtile, SINGLE-buffered LDS
// (20.5 KB -> 4 blocks/CU co-resident, VGPR-capped; inter-block overlap hides
// the per-iter staging latency) + XCD-aware block swizzle: the 4 col-tiles
// sharing one row-group land on the SAME XCD so A re-reads hit that XCD's L2.
// NO min-waves hint (rounds 1-3: any cap below the live set spills acc).
// ---------------------------------------------------------------------------
template <int K, bool GATHER>
__global__ __launch_bounds__(256) void xg_gemm(
    const float* __restrict__ A, const int* __restrict__ idx,
    const float* __restrict__ W, const float* __restrict__ b1,
    const float* __restrict__ b2, float* __restrict__ out)
{
    __shared__ float As[128][20];
    __shared__ float Bs[128][20];
    __shared__ int   idx_s[128];

    // bid = xcd + 8*(col_tile + 4*row_group); row_tile = row_group*8 + xcd
    // -> all 4 col-tiles of a row-tile map to the same XCD (bid % 8 equal).
    const int bid   = blockIdx.x;
    const int xcd   = bid & 7;
    const int rest  = bid >> 3;
    const int ct    = rest & 3;
    const int rgrp  = rest >> 2;
    const int row0  = (rgrp * 8 + xcd) * 128;
    const int col0  = ct * 128;

    const int tid  = threadIdx.x;
    const int tx   = tid & 15;
    const int ty   = tid >> 4;

    if (GATHER) {
        if (tid < 128) idx_s[tid] = idx[row0 + tid];
        __syncthreads();
    }

    float acc[8][8];
#pragma unroll
    for (int r = 0; r < 8; ++r)
#pragma unroll
        for (int j = 0; j < 8; ++j) acc[r][j] = 0.f;

#pragma unroll 1
    for (int k0 = 0; k0 < K; k0 += 20) {
        // stage A tile: 128 rows x 20 floats = 640 float4
        for (int e = tid; e < 640; e += 256) {
            int r = e / 5, kq = e % 5;
            int src = GATHER ? idx_s[r] : (row0 + r);
            *(float4*)(&As[r][kq * 4]) =
                *(const float4*)(A + (size_t)src * K + k0 + kq * 4);
        }
        // stage W tile: 128 gate-rows x 20 floats, zero-fill rows >= 400
        for (int e = tid; e < 640; e += 256) {
            int r = e / 5, kq = e % 5;
            int wrow = col0 + r;
            float4 v = make_float4(0.f, 0.f, 0.f, 0.f);
            if (wrow < GATES)
                v = *(const float4*)(W + (size_t)wrow * K + k0 + kq * 4);
            *(float4*)(&Bs[r][kq * 4]) = v;
        }
        __syncthreads();

#pragma unroll
        for (int kk = 0; kk < 20; kk += 4) {
            float4 a4[8];
#pragma unroll
            for (int r = 0; r < 8; ++r)
                a4[r] = *(const float4*)(&As[ty + 16 * r][kk]);
#pragma unroll
            for (int j = 0; j < 8; ++j) {
                float4 b4 = *(const float4*)(&Bs[tx + 16 * j][kk]);
#pragma unroll
                for (int r = 0; r < 8; ++r) {
                    acc[r][j] += a4[r].x * b4.x + a4[r].y * b4.y +
                                 a4[r].z * b4.z + a4[r].w * b4.w;
                }
            }
        }
        __syncthreads();   // protect As/Bs before next overwrite
    }

#pragma unroll
    for (int r = 0; r < 8; ++r) {
        int row = row0 + ty + 16 * r;
#pragma unroll
        for (int j = 0; j < 8; ++j) {
            int col = col0 + tx + 16 * j;
            if (col < GATES)
                out[(size_t)row * GATES + col] = acc[r][j] + b1[col] + b2[col];
        }
    }
}

// ---------------------------------------------------------------------------
// Recurrent scan v4 (k-split quads):
//   thread 4j+gt: hidden j, quad-lane gt owns k-range [gt*25, gt*25+25)
//   of ALL FOUR gate rows of hidden j (w4[4][28], zero-padded to 28).
//   Per step: 7 ds_read_b128 of its h-quarter (vs 25 full-h reads),
//   4 partial dots, quad butterfly __shfl_xor reduce, activation exchange
//   via 3 shfls, redundant c/h update in all 4 lanes. One barrier/step,
//   h double-buffered in padded [4][28] layout; xg staged in 32-step chunks.
// ---------------------------------------------------------------------------
__global__ __launch_bounds__(448) void lstm_recur(
    const float* __restrict__ xg,    // [B, T, 400]
    const float* __restrict__ w_hh,  // [400, 100]
    const int*   __restrict__ lengths,
    float* __restrict__ hs)          // [B, T, 100]
{
    const int b   = blockIdx.x;
    const int tid = threadIdx.x;
    const bool active = (tid < 400);
    const int j    = tid >> 2;      // hidden index (active: 0..99)
    const int gt   = tid & 3;       // k-quarter / gate-type lane

    __shared__ float xg_s[32 * GATES];   // 51.2 KB chunk of xg
    __shared__ float h_s[2][112];        // padded 4 x 28 segments

    float w4[4][28];
    if (active) {
#pragma unroll
        for (int g = 0; g < 4; ++g) {
            const float* wr = w_hh + (size_t)(g * HID + j) * HID + gt * 25;
#pragma unroll
            for (int i = 0; i < 28; ++i)
                w4[g][i] = (i < 25) ? wr[i] : 0.f;
        }
    }
    // zero both h buffers including pads (pads never rewritten)
    for (int i = tid; i < 224; i += 448) ((float*)h_s)[i] = 0.f;

    float c_reg = 0.f, h_reg = 0.f;
    const int len = lengths[b];
    const float* xgb = xg + (size_t)b * T_STEPS * GATES;
    float*       hsb = hs + (size_t)b * T_STEPS * HID;

    const bool is0 = (gt == 0), is1 = (gt == 1), is2 = (gt == 2);
    const int  hoff = gt * 28;
    const int  seg  = (j / 25) * 28 + (j % 25);   // h write position

    for (int t = 0; t < T_STEPS; ++t) {
        if ((t & 31) == 0) {
            // previous step's bottom barrier ensures old chunk reads done
            const float4* src = (const float4*)(xgb + (size_t)t * GATES);
            float4*       dst = (float4*)xg_s;
            for (int i = tid; i < 3200; i += 448) dst[i] = src[i];
            __syncthreads();
        }

        float s0 = 0.f, s1 = 0.f, s2 = 0.f, s3 = 0.f;
        if (active) {
            const float* hb = h_s[t & 1] + hoff;
#pragma unroll
            for (int i = 0; i < 28; i += 4) {
                float4 h4 = *(const float4*)(hb + i);
                s0 += w4[0][i] * h4.x + w4[0][i+1] * h4.y +
                      w4[0][i+2] * h4.z + w4[0][i+3] * h4.w;
                s1 += w4[1][i] * h4.x + w4[1][i+1] * h4.y +
                      w4[1][i+2] * h4.z + w4[1][i+3] * h4.w;
                s2 += w4[2][i] * h4.x + w4[2][i+1] * h4.y +
                      w4[2][i+2] * h4.z + w4[2][i+3] * h4.w;
                s3 += w4[3][i] * h4.x + w4[3][i+1] * h4.y +
                      w4[3][i+2] * h4.z + w4[3][i+3] * h4.w;
            }
        }
        // quad butterfly all-reduce: every lane gets full dot of each gate
        s0 += __shfl_xor(s0, 1); s0 += __shfl_xor(s0, 2);
        s1 += __shfl_xor(s1, 1); s1 += __shfl_xor(s1, 2);
        s2 += __shfl_xor(s2, 1); s2 += __shfl_xor(s2, 2);
        s3 += __shfl_xor(s3, 1); s3 += __shfl_xor(s3, 2);

        float sg = is0 ? s0 : is1 ? s1 : is2 ? s2 : s3;
        float pre = 0.f;
        if (active)
            pre = sg + xg_s[(t & 31) * GATES + gt * HID + j];

        float p0 = is2 ? tanh_f(pre) : sigm_f(pre);
        float p1 = __shfl_xor(p0, 1);
        float p2 = __shfl_xor(p0, 2);
        float p3 = __shfl_xor(p1, 2);
        // act of gate k = p[gt ^ k]
        float iv = is0 ? p0 : is1 ? p1 : is2 ? p2 : p3;
        float fv = is0 ? p1 : is1 ? p0 : is2 ? p3 : p2;
        float gv = is0 ? p2 : is1 ? p3 : is2 ? p0 : p1;
        float ov = is0 ? p3 : is1 ? p2 : is2 ? p1 : p0;

        float c_new = fv * c_reg + iv * gv;
        float h_new = ov * tanh_f(c_new);
        bool  m     = (t < len);
        c_reg = m ? c_new : c_reg;
        h_reg = m ? h_new : h_reg;

        if (active && gt == 0) {
            h_s[(t & 1) ^ 1][seg] = h_reg;
            hsb[(size_t)t * HID + j] = h_reg;
        }
        __syncthreads();
    }
}

// ---------------------------------------------------------------------------
// Final linear head
// ---------------------------------------------------------------------------
__global__ __launch_bounds__(64) void fc_kernel(
    const float* __restrict__ hs, const float* __restrict__ w_fc,
    const float* __restrict__ b_fc, float* __restrict__ out)
{
    int tid = blockIdx.x * 64 + threadIdx.x;
    if (tid >= BATCH * 3) return;
    int b = tid / 3, o = tid % 3;
    const float* h = hs + ((size_t)b * T_STEPS + (T_STEPS - 1)) * HID;
    float acc = b_fc[o];
    for (int j = 0; j < HID; ++j) acc += h[j] * w_fc[o * HID + j];
    out[b * 3 + o] = acc;
}

extern "C" void kernel_launch(void* const* d_in, const int* in_sizes, int n_in,
                              void* d_out, int out_size, void* d_ws, size_t ws_size,
                              hipStream_t stream)
{
    const int*   x       = (const int*)  d_in[0];
    const int*   lengths = (const int*)  d_in[1];
    const float* emb     = (const float*)d_in[2];
    const float* w_ih0   = (const float*)d_in[3];
    const float* w_hh0   = (const float*)d_in[4];
    const float* b_ih0   = (const float*)d_in[5];
    const float* b_hh0   = (const float*)d_in[6];
    const float* w_ih1   = (const float*)d_in[7];
    const float* w_hh1   = (const float*)d_in[8];
    const float* b_ih1   = (const float*)d_in[9];
    const float* b_hh1   = (const float*)d_in[10];
    const float* w_ih2   = (const float*)d_in[11];
    const float* w_hh2   = (const float*)d_in[12];
    const float* b_ih2   = (const float*)d_in[13];
    const float* b_hh2   = (const float*)d_in[14];
    const float* w_fc    = (const float*)d_in[15];
    const float* b_fc    = (const float*)d_in[16];
    float* out = (float*)d_out;

    float* xg = (float*)d_ws;                  // [BT, 400]  ~210 MB
    float* hs = xg + (size_t)BT * GATES;       // [BT, 100]  ~52 MB

    const int nblk = (BT / 128) * 4;   // 4096, XCD-swizzled inside kernel

    // Layer 0: embedding gather fused into A-stage, K=300
    xg_gemm<300, true><<<nblk, 256, 0, stream>>>(emb, x, w_ih0, b_ih0, b_hh0, xg);
    lstm_recur<<<BATCH, 448, 0, stream>>>(xg, w_hh0, lengths, hs);

    // Layer 1
    xg_gemm<100, false><<<nblk, 256, 0, stream>>>(hs, nullptr, w_ih1, b_ih1, b_hh1, xg);
    lstm_recur<<<BATCH, 448, 0, stream>>>(xg, w_hh1, lengths, hs);

    // Layer 2
    xg_gemm<100, false><<<nblk, 256, 0, stream>>>(hs, nullptr, w_ih2, b_ih2, b_hh2, xg);
    lstm_recur<<<BATCH, 448, 0, stream>>>(xg, w_hh2, lengths, hs);

    // Head
    fc_kernel<<<(BATCH * 3 + 63) / 64, 64, 0, stream>>>(hs, w_fc, b_fc, out);
}